// Round 18
// baseline (272.126 us; speedup 1.0000x reference)
//
#include <hip/hip_runtime.h>
#include <math.h>

#ifndef M_PI
#define M_PI 3.14159265358979323846
#endif

namespace {

constexpr int kDim = 768;
constexpr int kNKW = 33;           // W/2+1
constexpr int kB = 8;
constexpr float kLambd = 0.01f;
constexpr size_t kXFElems = (size_t)kB * kNKW * 64 * kDim;  // 12,976,128

typedef __attribute__((ext_vector_type(8))) __bf16 bf16x8;
typedef __attribute__((ext_vector_type(8))) short short8;
typedef __attribute__((ext_vector_type(4))) float f32x4;

// Pre-transposed bf16 MLP weights: [mtx][nb][k_out][d], mtx: w1r,w1i,w2r,w2i
alignas(16) __device__ unsigned short g_wT[4 * 8 * 96 * 96];
// DFT twiddle tables (bf16): g_twC[a*64+b]=0.125*cos, g_twS=0.125*sin
alignas(16) __device__ unsigned short g_twC[64 * 64];
alignas(16) __device__ unsigned short g_twS[64 * 64];
// irfft tables: [w*64+kw] = alpha*cos / -alpha*sin, 0 for kw>=33
alignas(16) __device__ unsigned short g_iwC[64 * 64];
alignas(16) __device__ unsigned short g_iwS[64 * 64];

// RNE float -> bf16 (inputs are normal floats; NaN not expected)
__device__ inline unsigned short f2bf(float f) {
  unsigned int u = __float_as_uint(f);
  unsigned int r = (u + 0x7FFFu + ((u >> 16) & 1u)) >> 16;
  return (unsigned short)r;
}

__device__ inline bf16x8 s2b(short8 s) { return __builtin_bit_cast(bf16x8, s); }
__device__ inline bf16x8 negb(short8 s) {
  s ^= (short)0x8000;
  return __builtin_bit_cast(bf16x8, s);
}

__device__ inline void gload_lds16(const void* g, void* l) {
  __builtin_amdgcn_global_load_lds(
      (const __attribute__((address_space(1))) unsigned int*)g,
      (__attribute__((address_space(3))) unsigned int*)l, 16, 0, 0);
}

// ---------------- 0c. twiddle table init (once per launch) -----------------
__global__ __launch_bounds__(256) void init_tables_kernel() {
  const int e = blockIdx.x * 256 + threadIdx.x;
  if (e >= 4096) return;
  const int a = e >> 6;
  const int bcol = e & 63;
  const float ang = (float)(2.0 * M_PI / 64.0) * (float)((a * bcol) & 63);
  float s_, c_;
  __sincosf(ang, &s_, &c_);
  g_twC[e] = f2bf(0.125f * c_);
  g_twS[e] = f2bf(0.125f * s_);
  unsigned short cv = 0, sv = 0;
  if (bcol < 33) {
    const float al = (bcol == 0 || bcol == 32) ? 0.125f : 0.25f;
    cv = f2bf(al * c_);
    sv = f2bf(-al * s_);
  }
  g_iwC[e] = cv;
  g_iwS[e] = sv;
}

// ---------------- 0a. fp32 -> bf16 conversion (Wb only) --------------------
__global__ __launch_bounds__(256) void cvt_f32_bf16_kernel(
    const float* __restrict__ in, unsigned short* __restrict__ out, int n4) {
  int i = blockIdx.x * 256 + threadIdx.x;
  if (i >= n4) return;
  const float4 v = reinterpret_cast<const float4*>(in)[i];
  ushort4 o;
  o.x = f2bf(v.x); o.y = f2bf(v.y); o.z = f2bf(v.z); o.w = f2bf(v.w);
  reinterpret_cast<ushort4*>(out)[i] = o;
}

// ---------------- 0b. MLP weight transpose+convert (once per launch) -------
__global__ __launch_bounds__(256) void cvt_w_kernel(
    const float* __restrict__ w1, const float* __restrict__ w2) {
  const int e = blockIdx.x * 256 + threadIdx.x;
  if (e >= 4 * 8 * 96 * 96) return;
  const int k = e % 96;
  const int d = (e / 96) % 96;
  const int nbm = e / 9216;  // mtx*8+nb
  const int mtx = nbm >> 3;
  const int nb = nbm & 7;
  const float* src =
      (mtx < 2 ? w1 : w2) + ((size_t)(mtx & 1) * 8 + nb) * 9216;
  g_wT[((size_t)nbm * 96 + k) * 96 + d] = f2bf(src[d * 96 + k]);
}

// ---------------- 1. bias GEMM via MFMA (r16 single-buffer) ----------------
__global__ __launch_bounds__(256) void mfma_gemm_kernel(
    const unsigned short* __restrict__ xbf, const unsigned short* __restrict__ wbf,
    const float* __restrict__ bb, float* __restrict__ out) {
  __shared__ unsigned short As[128 * 32];  // [row][k] 8KB
  __shared__ unsigned short Bs[128 * 32];  // [n][k]   8KB
  const int t = threadIdx.x;
  const int lane = t & 63;
  const int wid = t >> 6;
  const int wm = wid >> 1;
  const int wn = wid & 1;
  const int id = blockIdx.x;
  const int swz = (id & 7) * 192 + (id >> 3);  // XCD chunk swizzle, bijective
  const int m0 = (swz / 6) * 128;
  const int n0 = (swz % 6) * 128;

  f32x4 acc[4][4];
#pragma unroll
  for (int i = 0; i < 4; ++i)
#pragma unroll
    for (int j = 0; j < 4; ++j) acc[i][j] = (f32x4){0.f, 0.f, 0.f, 0.f};

  char* AsB = (char*)As;
  char* BsB = (char*)Bs;
  const int cl = lane & 15;
  const int kg = lane >> 4;  // 0..3

  for (int k0 = 0; k0 < 768; k0 += 32) {
#pragma unroll
    for (int i = 0; i < 2; ++i) {
      const int off = (wid * 2 + i) * 1024 + lane * 16;  // byte off in tile
      const int row = off >> 6;
      const int kb = off & 63;
      const char* gA = (const char*)xbf + ((size_t)(m0 + row) * 768 + k0) * 2 + kb;
      gload_lds16(gA, AsB + (wid * 2 + i) * 1024);
      const char* gB = (const char*)wbf + ((size_t)(n0 + row) * 768 + k0) * 2 + kb;
      gload_lds16(gB, BsB + (wid * 2 + i) * 1024);
    }
    asm volatile("s_waitcnt vmcnt(0)" ::: "memory");
    __syncthreads();

    bf16x8 av[4], bv[4];
#pragma unroll
    for (int mi = 0; mi < 4; ++mi) {
      const int r = wm * 64 + mi * 16 + cl;
      av[mi] = *reinterpret_cast<const bf16x8*>(AsB + r * 64 + kg * 16);
    }
#pragma unroll
    for (int ni = 0; ni < 4; ++ni) {
      const int r = wn * 64 + ni * 16 + cl;
      bv[ni] = *reinterpret_cast<const bf16x8*>(BsB + r * 64 + kg * 16);
    }
#pragma unroll
    for (int mi = 0; mi < 4; ++mi)
#pragma unroll
      for (int ni = 0; ni < 4; ++ni)
        acc[mi][ni] = __builtin_amdgcn_mfma_f32_16x16x32_bf16(
            av[mi], bv[ni], acc[mi][ni], 0, 0, 0);
    __syncthreads();
  }

#pragma unroll
  for (int ni = 0; ni < 4; ++ni) {
    const int n = n0 + wn * 64 + ni * 16 + cl;
    const float bias = bb[n];
#pragma unroll
    for (int mi = 0; mi < 4; ++mi) {
      const int m = m0 + wm * 64 + mi * 16 + kg * 4;
#pragma unroll
      for (int r = 0; r < 4; ++r) {
        out[(size_t)(m + r) * 768 + n] = acc[mi][ni][r] + bias;
      }
    }
  }
}

// ---------------- 2. forward row rFFT via MFMA (round-16 structure) --------
__global__ __launch_bounds__(256) void rfft_row_mfma_kernel(
    const float* __restrict__ x, unsigned short* __restrict__ xbf,
    unsigned short* __restrict__ XFr, unsigned short* __restrict__ XFi) {
  __shared__ alignas(16) unsigned short Cs[48 * 80];   //  0.125*cos [kh][w]
  __shared__ alignas(16) unsigned short Ss[48 * 80];   // -0.125*sin
  __shared__ alignas(16) unsigned short xs[64 * 66];   // [w][c] stride 66
  const int t = threadIdx.x;
  for (int e = t; e < 48 * 64; e += 256) {
    const int kh = e >> 6;
    const int w = e & 63;
    const float ang = (float)(2.0 * M_PI / 64.0) * (float)((kh * w) & 63);
    float s_, c_;
    __sincosf(ang, &s_, &c_);
    Cs[kh * 80 + w] = f2bf(0.125f * c_);
    Ss[kh * 80 + w] = f2bf(-0.125f * s_);
  }

  const int lane = t & 63;
  const int wv = t >> 6;       // wave id
  const int cl = lane & 15;
  const int kg = lane >> 4;    // 0..3
  const int bh = blockIdx.x;   // b*64 + h
  const int b = bh >> 6;
  const int h = bh & 63;
  const int c0 = blockIdx.y * 64;

  // ---- stage: wave wv covers w = wv*16..+15; lane -> (w parity, 2 chans) --
  {
    const float* xrow = x + (size_t)bh * (64 * 768) + c0;
    unsigned short* xbrow = xbf + (size_t)bh * (64 * 768) + c0;
    const int wofs = lane >> 5;        // 0..1
    const int c2 = (lane & 31) * 2;    // even channel
#pragma unroll
    for (int it = 0; it < 8; ++it) {
      const int w = wv * 16 + it * 2 + wofs;
      const float2 v = *reinterpret_cast<const float2*>(xrow + (size_t)w * 768 + c2);
      ushort2 bv;
      bv.x = f2bf(v.x);
      bv.y = f2bf(v.y);
      *reinterpret_cast<ushort2*>(xbrow + (size_t)w * 768 + c2) = bv;
      *reinterpret_cast<ushort2*>(xs + w * 66 + c2) = bv;
    }
  }
  __syncthreads();

  // A fragments: lane holds x[w = kf*32+kg*8+j][c = c0 + wv*16 + cl]
  const int cA = wv * 16 + cl;
  short8 ax[2];
#pragma unroll
  for (int kf = 0; kf < 2; ++kf) {
#pragma unroll
    for (int j = 0; j < 8; ++j)
      ax[kf][j] = (short)xs[(kf * 32 + kg * 8 + j) * 66 + cA];
  }

  f32x4 aR[3], aI[3];
#pragma unroll
  for (int nt = 0; nt < 3; ++nt) {
    aR[nt] = (f32x4){0.f, 0.f, 0.f, 0.f};
    aI[nt] = (f32x4){0.f, 0.f, 0.f, 0.f};
  }

#pragma unroll
  for (int nt = 0; nt < 3; ++nt) {
#pragma unroll
    for (int kf = 0; kf < 2; ++kf) {
      const int row = nt * 16 + cl;       // kh
      const int w0 = kf * 32 + kg * 8;
      const bf16x8 bc = *reinterpret_cast<const bf16x8*>(Cs + row * 80 + w0);
      const bf16x8 bs = *reinterpret_cast<const bf16x8*>(Ss + row * 80 + w0);
      aR[nt] = __builtin_amdgcn_mfma_f32_16x16x32_bf16(s2b(ax[kf]), bc, aR[nt], 0, 0, 0);
      aI[nt] = __builtin_amdgcn_mfma_f32_16x16x32_bf16(s2b(ax[kf]), bs, aI[nt], 0, 0, 0);
    }
  }

  // store: lane holds kh = nt*16+cl, c = c0 + wv*16 + kg*4 + (0..3)
  const int cD = c0 + wv * 16 + kg * 4;
#pragma unroll
  for (int nt = 0; nt < 3; ++nt) {
    const int kh = nt * 16 + cl;
    if (kh <= 32) {
      const size_t off = (((size_t)b * kNKW + kh) * 64 + h) * 768 + cD;
      ushort4 vr, vi;
      vr.x = f2bf(aR[nt][0]); vr.y = f2bf(aR[nt][1]);
      vr.z = f2bf(aR[nt][2]); vr.w = f2bf(aR[nt][3]);
      vi.x = f2bf(aI[nt][0]); vi.y = f2bf(aI[nt][1]);
      vi.z = f2bf(aI[nt][2]); vi.w = f2bf(aI[nt][3]);
      *reinterpret_cast<ushort4*>(XFr + off) = vr;
      *reinterpret_cast<ushort4*>(XFi + off) = vi;
    }
  }
}

// ---------------- 3+4+5 fused: col FFT -> MLP -> col iFFT ------------------
// Layout-flipping pipeline: every stage reads AND writes vectorized.
//   stage: global [h][c] -> buf0 [c][h]    (transpose, scalar writes)
//   A (swapped, tw in regs): buf0 [c][h]  -> buf1 [kh][c]   (u4 writes)
//   B (MLP1):                buf1 [kh][c] -> buf0 [kh][k']  (scalar writes)
//   C (MLP2):                buf0 [kh][k']-> buf1 [k''][kh] (u4 writes)
//   D (swapped, tw in regs): buf1 [c][kh] -> global [h][c]  (u4 writes)
__global__ __launch_bounds__(256) void spectral_mid_kernel(
    unsigned short* __restrict__ Xr, unsigned short* __restrict__ Xi,
    const float* __restrict__ b1, const float* __restrict__ b2) {
  __shared__ alignas(16) unsigned short bR0[96 * 72];  // 13.5KB
  __shared__ alignas(16) unsigned short bI0[96 * 72];
  __shared__ alignas(16) unsigned short bR1[96 * 72];
  __shared__ alignas(16) unsigned short bI1[96 * 72];
  const int t = threadIdx.x;
  const int lane = t & 63;
  const int wv = t >> 6;    // wave 0..3
  const int cl = lane & 15;
  const int kg = lane >> 4;
  const int nb = blockIdx.y;
  const size_t gbase = (size_t)blockIdx.x * (64 * 768) + nb * 96;

  // twiddle fragments: row = wv*16+cl, k = kf*32+kg*8 (symmetric: A and D)
  short8 pcs[2], pss[2];
#pragma unroll
  for (int kf = 0; kf < 2; ++kf) {
    const int row = wv * 16 + cl;
    const int k0 = kf * 32 + kg * 8;
    pcs[kf] = *reinterpret_cast<const short8*>(g_twC + row * 64 + k0);
    pss[kf] = *reinterpret_cast<const short8*>(g_twS + row * 64 + k0);
  }

  // ---- stage: global [h][c] -> buf0 [c][h] (stride 72) ----
  {
    const int h = t >> 2;
    const int q = t & 3;
    const size_t gof = gbase + (size_t)h * 768 + q * 24;
#pragma unroll
    for (int v = 0; v < 3; ++v) {
      const short8 vr = *reinterpret_cast<const short8*>(Xr + gof + v * 8);
      const short8 vi = *reinterpret_cast<const short8*>(Xi + gof + v * 8);
#pragma unroll
      for (int e = 0; e < 8; ++e) {
        const int c = q * 24 + v * 8 + e;
        bR0[c * 72 + h] = (unsigned short)vr[e];
        bI0[c * 72 + h] = (unsigned short)vi[e];
      }
    }
  }
  __syncthreads();

  f32x4 accR[6], accI[6];

  // ===== stage A: Y[kh][c] = sum_h tw[kh][h] X[h][c]  (swapped) =====
#pragma unroll
  for (int mt = 0; mt < 6; ++mt) {
    accR[mt] = (f32x4){0.f, 0.f, 0.f, 0.f};
    accI[mt] = (f32x4){0.f, 0.f, 0.f, 0.f};
  }
#pragma unroll
  for (int mt = 0; mt < 6; ++mt) {
#pragma unroll
    for (int kf = 0; kf < 2; ++kf) {
      const int ro = (mt * 16 + cl) * 72 + kf * 32 + kg * 8;
      const short8 axr = *reinterpret_cast<const short8*>(bR0 + ro);
      const short8 axi = *reinterpret_cast<const short8*>(bI0 + ro);
      // Yr = C*Xr + S*Xi ; Yi = C*Xi - S*Xr
      accR[mt] = __builtin_amdgcn_mfma_f32_16x16x32_bf16(s2b(axr), s2b(pcs[kf]), accR[mt], 0, 0, 0);
      accR[mt] = __builtin_amdgcn_mfma_f32_16x16x32_bf16(s2b(axi), s2b(pss[kf]), accR[mt], 0, 0, 0);
      accI[mt] = __builtin_amdgcn_mfma_f32_16x16x32_bf16(s2b(axi), s2b(pcs[kf]), accI[mt], 0, 0, 0);
      accI[mt] = __builtin_amdgcn_mfma_f32_16x16x32_bf16(negb(axr), s2b(pss[kf]), accI[mt], 0, 0, 0);
    }
  }
  // write buf1 [kh][c] stride 104: lane col kh = wv*16+cl, rows c consecutive
#pragma unroll
  for (int mt = 0; mt < 6; ++mt) {
    const int kh = wv * 16 + cl;
    const int c4 = mt * 16 + kg * 4;
    ushort4 vr, vi;
    vr.x = f2bf(accR[mt][0]); vr.y = f2bf(accR[mt][1]);
    vr.z = f2bf(accR[mt][2]); vr.w = f2bf(accR[mt][3]);
    vi.x = f2bf(accI[mt][0]); vi.y = f2bf(accI[mt][1]);
    vi.z = f2bf(accI[mt][2]); vi.w = f2bf(accI[mt][3]);
    *reinterpret_cast<ushort4*>(bR1 + kh * 104 + c4) = vr;
    *reinterpret_cast<ushort4*>(bI1 + kh * 104 + c4) = vi;
  }
  __syncthreads();

  const unsigned short* wt1r = g_wT + (size_t)(0 * 8 + nb) * 9216;
  const unsigned short* wt1i = g_wT + (size_t)(1 * 8 + nb) * 9216;
  const unsigned short* wt2r = g_wT + (size_t)(2 * 8 + nb) * 9216;
  const unsigned short* wt2i = g_wT + (size_t)(3 * 8 + nb) * 9216;

  // ===== stage B: MLP layer 1: buf1 [kh][c] -> buf0 [kh][k'] =====
#pragma unroll
  for (int nt = 0; nt < 6; ++nt) {
    accR[nt] = (f32x4){0.f, 0.f, 0.f, 0.f};
    accI[nt] = (f32x4){0.f, 0.f, 0.f, 0.f};
  }
#pragma unroll
  for (int kk = 0; kk < 3; ++kk) {
    const int ko = kk * 32 + kg * 8;
    const int ro = (wv * 16 + cl) * 104 + ko;
    const short8 ayr = *reinterpret_cast<const short8*>(bR1 + ro);
    const short8 ayi = *reinterpret_cast<const short8*>(bI1 + ro);
    const bf16x8 ar = s2b(ayr);
    const bf16x8 ai = s2b(ayi);
    const bf16x8 ain = negb(ayi);
#pragma unroll
    for (int nt = 0; nt < 6; ++nt) {
      const int rw = (nt * 16 + cl) * 96 + ko;
      const bf16x8 wr_ = *reinterpret_cast<const bf16x8*>(wt1r + rw);
      const bf16x8 wi_ = *reinterpret_cast<const bf16x8*>(wt1i + rw);
      accR[nt] = __builtin_amdgcn_mfma_f32_16x16x32_bf16(ar, wr_, accR[nt], 0, 0, 0);
      accR[nt] = __builtin_amdgcn_mfma_f32_16x16x32_bf16(ain, wi_, accR[nt], 0, 0, 0);
      accI[nt] = __builtin_amdgcn_mfma_f32_16x16x32_bf16(ar, wi_, accI[nt], 0, 0, 0);
      accI[nt] = __builtin_amdgcn_mfma_f32_16x16x32_bf16(ai, wr_, accI[nt], 0, 0, 0);
    }
  }
  __syncthreads();  // buf0 reads from stage A done (long done); buf1 reads done
  // bias + relu -> buf0 [kh][k'] (scalar writes)
#pragma unroll
  for (int nt = 0; nt < 6; ++nt) {
    const int col = nt * 16 + cl;
    const float br = b1[nb * 96 + col];
    const float bi = b1[768 + nb * 96 + col];
#pragma unroll
    for (int r = 0; r < 4; ++r) {
      const int kh = wv * 16 + kg * 4 + r;
      bR0[kh * 104 + col] = f2bf(fmaxf(accR[nt][r] + br, 0.f));
      bI0[kh * 104 + col] = f2bf(fmaxf(accI[nt][r] + bi, 0.f));
    }
  }
  __syncthreads();

  // ===== stage C: MLP layer 2: buf0 [kh][k'] -> buf1 [k''][kh] =====
#pragma unroll
  for (int nt = 0; nt < 6; ++nt) {
    accR[nt] = (f32x4){0.f, 0.f, 0.f, 0.f};
    accI[nt] = (f32x4){0.f, 0.f, 0.f, 0.f};
  }
#pragma unroll
  for (int kk = 0; kk < 3; ++kk) {
    const int ko = kk * 32 + kg * 8;
    const int ro = (wv * 16 + cl) * 104 + ko;
    const short8 ayr = *reinterpret_cast<const short8*>(bR0 + ro);
    const short8 ayi = *reinterpret_cast<const short8*>(bI0 + ro);
    const bf16x8 ar = s2b(ayr);
    const bf16x8 ai = s2b(ayi);
    const bf16x8 ain = negb(ayi);
#pragma unroll
    for (int nt = 0; nt < 6; ++nt) {
      const int rw = (nt * 16 + cl) * 96 + ko;
      const bf16x8 wr_ = *reinterpret_cast<const bf16x8*>(wt2r + rw);
      const bf16x8 wi_ = *reinterpret_cast<const bf16x8*>(wt2i + rw);
      accR[nt] = __builtin_amdgcn_mfma_f32_16x16x32_bf16(ar, wr_, accR[nt], 0, 0, 0);
      accR[nt] = __builtin_amdgcn_mfma_f32_16x16x32_bf16(ain, wi_, accR[nt], 0, 0, 0);
      accI[nt] = __builtin_amdgcn_mfma_f32_16x16x32_bf16(ar, wi_, accI[nt], 0, 0, 0);
      accI[nt] = __builtin_amdgcn_mfma_f32_16x16x32_bf16(ai, wr_, accI[nt], 0, 0, 0);
    }
  }
  __syncthreads();  // buf1 reads (stage B) done before overwrite
  // bias + softshrink -> buf1 [k''][kh] stride 72 (vector writes)
#pragma unroll
  for (int nt = 0; nt < 6; ++nt) {
    const int col = nt * 16 + cl;  // k''
    const float br = b2[nb * 96 + col];
    const float bi = b2[768 + nb * 96 + col];
    float pr[4], pi[4];
#pragma unroll
    for (int r = 0; r < 4; ++r) {
      float vr = accR[nt][r] + br;
      float vi = accI[nt][r] + bi;
      vr = (vr > kLambd) ? (vr - kLambd) : ((vr < -kLambd) ? (vr + kLambd) : 0.f);
      vi = (vi > kLambd) ? (vi - kLambd) : ((vi < -kLambd) ? (vi + kLambd) : 0.f);
      pr[r] = vr; pi[r] = vi;
    }
    const int kh4 = wv * 16 + kg * 4;
    ushort4 vr4, vi4;
    vr4.x = f2bf(pr[0]); vr4.y = f2bf(pr[1]); vr4.z = f2bf(pr[2]); vr4.w = f2bf(pr[3]);
    vi4.x = f2bf(pi[0]); vi4.y = f2bf(pi[1]); vi4.z = f2bf(pi[2]); vi4.w = f2bf(pi[3]);
    *reinterpret_cast<ushort4*>(bR1 + col * 72 + kh4) = vr4;
    *reinterpret_cast<ushort4*>(bI1 + col * 72 + kh4) = vi4;
  }
  __syncthreads();

  // ===== stage D: out[h][c] = sum_kh tw[h][kh] Y[kh][c]  (swapped) =====
#pragma unroll
  for (int mt = 0; mt < 6; ++mt) {
    accR[mt] = (f32x4){0.f, 0.f, 0.f, 0.f};
    accI[mt] = (f32x4){0.f, 0.f, 0.f, 0.f};
  }
#pragma unroll
  for (int mt = 0; mt < 6; ++mt) {
#pragma unroll
    for (int kf = 0; kf < 2; ++kf) {
      const int ro = (mt * 16 + cl) * 72 + kf * 32 + kg * 8;
      const short8 ayr = *reinterpret_cast<const short8*>(bR1 + ro);
      const short8 ayi = *reinterpret_cast<const short8*>(bI1 + ro);
      // Or = C*Yr - S*Yi ; Oi = C*Yi + S*Yr
      accR[mt] = __builtin_amdgcn_mfma_f32_16x16x32_bf16(s2b(ayr), s2b(pcs[kf]), accR[mt], 0, 0, 0);
      accR[mt] = __builtin_amdgcn_mfma_f32_16x16x32_bf16(negb(ayi), s2b(pss[kf]), accR[mt], 0, 0, 0);
      accI[mt] = __builtin_amdgcn_mfma_f32_16x16x32_bf16(s2b(ayi), s2b(pcs[kf]), accI[mt], 0, 0, 0);
      accI[mt] = __builtin_amdgcn_mfma_f32_16x16x32_bf16(s2b(ayr), s2b(pss[kf]), accI[mt], 0, 0, 0);
    }
  }
  // global write: lane col h = wv*16+cl, rows c consecutive -> ushort4
#pragma unroll
  for (int mt = 0; mt < 6; ++mt) {
    const int h = wv * 16 + cl;
    const int c4 = mt * 16 + kg * 4;
    const size_t off = gbase + (size_t)h * 768 + c4;
    ushort4 vr, vi;
    vr.x = f2bf(accR[mt][0]); vr.y = f2bf(accR[mt][1]);
    vr.z = f2bf(accR[mt][2]); vr.w = f2bf(accR[mt][3]);
    vi.x = f2bf(accI[mt][0]); vi.y = f2bf(accI[mt][1]);
    vi.z = f2bf(accI[mt][2]); vi.w = f2bf(accI[mt][3]);
    *reinterpret_cast<ushort4*>(Xr + off) = vr;
    *reinterpret_cast<ushort4*>(Xi + off) = vi;
  }
}

// ---------------- 6. inverse row rDFT + accumulate via MFMA (swapped) ------
__global__ __launch_bounds__(256) void irfft_row_add_mfma_kernel(
    const unsigned short* __restrict__ Zr, const unsigned short* __restrict__ Zi,
    float* __restrict__ out) {
  const int t = threadIdx.x;
  const int lane = t & 63;
  const int wv = t >> 6;
  const int cl = lane & 15;
  const int kg = lane >> 4;
  const int bh = blockIdx.x;  // b*64 + h
  const int b = bh >> 6;
  const int h = bh & 63;
  const int cb = blockIdx.y * 64 + wv * 16;  // wave's 16-channel strip

  // ---- prefetch irfft table fragments ----
  short8 pbc[4][2], pbs[4][2];  // [nt][kf]
#pragma unroll
  for (int nt = 0; nt < 4; ++nt) {
#pragma unroll
    for (int kf = 0; kf < 2; ++kf) {
      const int row = nt * 16 + cl;
      const int kw0 = kf * 32 + kg * 8;
      pbc[nt][kf] = *reinterpret_cast<const short8*>(g_iwC + row * 64 + kw0);
      pbs[nt][kf] = *reinterpret_cast<const short8*>(g_iwS + row * 64 + kw0);
    }
  }

  // A fragments: lane holds Z[c = cb + cl][kw = kf*32+kg*8+j]
  const int cA = cb + cl;
  short8 azr[2], azi[2];
#pragma unroll
  for (int kf = 0; kf < 2; ++kf) {
#pragma unroll
    for (int j = 0; j < 8; ++j) {
      const int kw = kf * 32 + kg * 8 + j;
      short zr = 0, zi = 0;
      if (kw < 33) {
        const size_t off = (((size_t)b * kNKW + kw) * 64 + h) * 768 + cA;
        zr = (short)Zr[off];
        zi = (short)Zi[off];
      }
      azr[kf][j] = zr;
      azi[kf][j] = zi;
    }
  }

  // preload accumulator with bias-path out values (float4 per lane)
  const int cD = cb + kg * 4;
  float* obase = out + ((size_t)bh * 64) * 768;
  f32x4 aO[4];
#pragma unroll
  for (int nt = 0; nt < 4; ++nt) {
    const int w = nt * 16 + cl;
    aO[nt] = *reinterpret_cast<const f32x4*>(obase + (size_t)w * 768 + cD);
  }

#pragma unroll
  for (int nt = 0; nt < 4; ++nt) {
#pragma unroll
    for (int kf = 0; kf < 2; ++kf) {
      aO[nt] = __builtin_amdgcn_mfma_f32_16x16x32_bf16(s2b(azr[kf]), s2b(pbc[nt][kf]), aO[nt], 0, 0, 0);
      aO[nt] = __builtin_amdgcn_mfma_f32_16x16x32_bf16(s2b(azi[kf]), s2b(pbs[nt][kf]), aO[nt], 0, 0, 0);
    }
  }

#pragma unroll
  for (int nt = 0; nt < 4; ++nt) {
    const int w = nt * 16 + cl;
    *reinterpret_cast<f32x4*>(obase + (size_t)w * 768 + cD) = aO[nt];
  }
}

}  // namespace

extern "C" void kernel_launch(void* const* d_in, const int* in_sizes, int n_in,
                              void* d_out, int out_size, void* d_ws,
                              size_t ws_size, hipStream_t stream) {
  (void)in_sizes; (void)n_in; (void)out_size;
  const float* x  = (const float*)d_in[0];
  const float* w1 = (const float*)d_in[1];
  const float* b1 = (const float*)d_in[2];
  const float* w2 = (const float*)d_in[3];
  const float* b2 = (const float*)d_in[4];
  const float* Wb = (const float*)d_in[5];
  const float* bb = (const float*)d_in[6];
  float* out = (float*)d_out;

  // ws layout (all bf16): xbf 48MB | wbf 1.2MB | XFr 26MB | XFi 26MB = 103.4MB
  if (ws_size < 2 * kXFElems * sizeof(float)) return;
  unsigned short* xbf = (unsigned short*)d_ws;      // 32768*768
  unsigned short* wbf = xbf + (size_t)32768 * 768;  // 768*768
  unsigned short* XFr = wbf + (size_t)768 * 768;    // kXFElems
  unsigned short* XFi = XFr + kXFElems;             // kXFElems

  // 0. one-shot conversions and tables
  init_tables_kernel<<<dim3(16), 256, 0, stream>>>();
  cvt_f32_bf16_kernel<<<dim3((768 * 768 / 4 + 255) / 256), 256, 0, stream>>>(
      Wb, wbf, 768 * 768 / 4);
  cvt_w_kernel<<<dim3(4 * 8 * 96 * 96 / 256), 256, 0, stream>>>(w1, w2);
  // 2. forward row rFFT on matrix cores (bf16 out) + fused x->bf16 for GEMM
  rfft_row_mfma_kernel<<<dim3(512, 12), 256, 0, stream>>>(x, xbf, XFr, XFi);
  // 1. bias path GEMM on matrix cores (writes d_out fully)
  mfma_gemm_kernel<<<dim3(1536), 256, 0, stream>>>(xbf, wbf, bb, out);
  // 3-5. fused: column FFT -> block-diag MLP -> column iFFT (in place)
  spectral_mid_kernel<<<dim3(264, 8), 256, 0, stream>>>(XFr, XFi, b1, b2);
  // 6. inverse row rDFT + add bias path on matrix cores
  irfft_row_add_mfma_kernel<<<dim3(512, 12), 256, 0, stream>>>(XFr, XFi, out);
}

// Round 19
// 244.971 us; speedup vs baseline: 1.1109x; 1.1109x over previous
//
#include <hip/hip_runtime.h>
#include <math.h>

#ifndef M_PI
#define M_PI 3.14159265358979323846
#endif

namespace {

constexpr int kDim = 768;
constexpr int kNKW = 33;           // W/2+1
constexpr int kB = 8;
constexpr float kLambd = 0.01f;
constexpr size_t kXFElems = (size_t)kB * kNKW * 64 * kDim;  // 12,976,128

typedef __attribute__((ext_vector_type(8))) __bf16 bf16x8;
typedef __attribute__((ext_vector_type(8))) short short8;
typedef __attribute__((ext_vector_type(4))) float f32x4;

// Pre-transposed bf16 MLP weights: [mtx][nb][k_out][d], mtx: w1r,w1i,w2r,w2i
alignas(16) __device__ unsigned short g_wT[4 * 8 * 96 * 96];
// DFT twiddle tables (bf16): g_twC[a*64+b]=0.125*cos, g_twS=0.125*sin
alignas(16) __device__ unsigned short g_twC[64 * 64];
alignas(16) __device__ unsigned short g_twS[64 * 64];
// irfft tables: [w*64+kw] = alpha*cos / -alpha*sin, 0 for kw>=33
alignas(16) __device__ unsigned short g_iwC[64 * 64];
alignas(16) __device__ unsigned short g_iwS[64 * 64];

// RNE float -> bf16 (inputs are normal floats; NaN not expected)
__device__ inline unsigned short f2bf(float f) {
  unsigned int u = __float_as_uint(f);
  unsigned int r = (u + 0x7FFFu + ((u >> 16) & 1u)) >> 16;
  return (unsigned short)r;
}

__device__ inline bf16x8 s2b(short8 s) { return __builtin_bit_cast(bf16x8, s); }
__device__ inline bf16x8 negb(short8 s) {
  s ^= (short)0x8000;
  return __builtin_bit_cast(bf16x8, s);
}

__device__ inline void gload_lds16(const void* g, void* l) {
  __builtin_amdgcn_global_load_lds(
      (const __attribute__((address_space(1))) unsigned int*)g,
      (__attribute__((address_space(3))) unsigned int*)l, 16, 0, 0);
}

// ---------------- 0c. twiddle table init (once per launch) -----------------
__global__ __launch_bounds__(256) void init_tables_kernel() {
  const int e = blockIdx.x * 256 + threadIdx.x;
  if (e >= 4096) return;
  const int a = e >> 6;
  const int bcol = e & 63;
  const float ang = (float)(2.0 * M_PI / 64.0) * (float)((a * bcol) & 63);
  float s_, c_;
  __sincosf(ang, &s_, &c_);
  g_twC[e] = f2bf(0.125f * c_);
  g_twS[e] = f2bf(0.125f * s_);
  unsigned short cv = 0, sv = 0;
  if (bcol < 33) {
    const float al = (bcol == 0 || bcol == 32) ? 0.125f : 0.25f;
    cv = f2bf(al * c_);
    sv = f2bf(-al * s_);
  }
  g_iwC[e] = cv;
  g_iwS[e] = sv;
}

// ---------------- 0a. fp32 -> bf16 conversion (Wb only) --------------------
__global__ __launch_bounds__(256) void cvt_f32_bf16_kernel(
    const float* __restrict__ in, unsigned short* __restrict__ out, int n4) {
  int i = blockIdx.x * 256 + threadIdx.x;
  if (i >= n4) return;
  const float4 v = reinterpret_cast<const float4*>(in)[i];
  ushort4 o;
  o.x = f2bf(v.x); o.y = f2bf(v.y); o.z = f2bf(v.z); o.w = f2bf(v.w);
  reinterpret_cast<ushort4*>(out)[i] = o;
}

// ---------------- 0b. MLP weight transpose+convert (once per launch) -------
__global__ __launch_bounds__(256) void cvt_w_kernel(
    const float* __restrict__ w1, const float* __restrict__ w2) {
  const int e = blockIdx.x * 256 + threadIdx.x;
  if (e >= 4 * 8 * 96 * 96) return;
  const int k = e % 96;
  const int d = (e / 96) % 96;
  const int nbm = e / 9216;  // mtx*8+nb
  const int mtx = nbm >> 3;
  const int nb = nbm & 7;
  const float* src =
      (mtx < 2 ? w1 : w2) + ((size_t)(mtx & 1) * 8 + nb) * 9216;
  g_wT[((size_t)nbm * 96 + k) * 96 + d] = f2bf(src[d * 96 + k]);
}

// ---------------- 1. bias GEMM via MFMA (single-buffer, r16) ---------------
__global__ __launch_bounds__(256) void mfma_gemm_kernel(
    const unsigned short* __restrict__ xbf, const unsigned short* __restrict__ wbf,
    const float* __restrict__ bb, float* __restrict__ out) {
  __shared__ unsigned short As[128 * 32];  // [row][k] 8KB
  __shared__ unsigned short Bs[128 * 32];  // [n][k]   8KB
  const int t = threadIdx.x;
  const int lane = t & 63;
  const int wid = t >> 6;
  const int wm = wid >> 1;
  const int wn = wid & 1;
  const int id = blockIdx.x;
  const int swz = (id & 7) * 192 + (id >> 3);  // XCD chunk swizzle, bijective
  const int m0 = (swz / 6) * 128;
  const int n0 = (swz % 6) * 128;

  f32x4 acc[4][4];
#pragma unroll
  for (int i = 0; i < 4; ++i)
#pragma unroll
    for (int j = 0; j < 4; ++j) acc[i][j] = (f32x4){0.f, 0.f, 0.f, 0.f};

  char* AsB = (char*)As;
  char* BsB = (char*)Bs;
  const int cl = lane & 15;
  const int kg = lane >> 4;  // 0..3

  for (int k0 = 0; k0 < 768; k0 += 32) {
#pragma unroll
    for (int i = 0; i < 2; ++i) {
      const int off = (wid * 2 + i) * 1024 + lane * 16;  // byte off in tile
      const int row = off >> 6;
      const int kb = off & 63;
      const char* gA = (const char*)xbf + ((size_t)(m0 + row) * 768 + k0) * 2 + kb;
      gload_lds16(gA, AsB + (wid * 2 + i) * 1024);
      const char* gB = (const char*)wbf + ((size_t)(n0 + row) * 768 + k0) * 2 + kb;
      gload_lds16(gB, BsB + (wid * 2 + i) * 1024);
    }
    asm volatile("s_waitcnt vmcnt(0)" ::: "memory");
    __syncthreads();

    bf16x8 av[4], bv[4];
#pragma unroll
    for (int mi = 0; mi < 4; ++mi) {
      const int r = wm * 64 + mi * 16 + cl;
      av[mi] = *reinterpret_cast<const bf16x8*>(AsB + r * 64 + kg * 16);
    }
#pragma unroll
    for (int ni = 0; ni < 4; ++ni) {
      const int r = wn * 64 + ni * 16 + cl;
      bv[ni] = *reinterpret_cast<const bf16x8*>(BsB + r * 64 + kg * 16);
    }
#pragma unroll
    for (int mi = 0; mi < 4; ++mi)
#pragma unroll
      for (int ni = 0; ni < 4; ++ni)
        acc[mi][ni] = __builtin_amdgcn_mfma_f32_16x16x32_bf16(
            av[mi], bv[ni], acc[mi][ni], 0, 0, 0);
    __syncthreads();
  }

#pragma unroll
  for (int ni = 0; ni < 4; ++ni) {
    const int n = n0 + wn * 64 + ni * 16 + cl;
    const float bias = bb[n];
#pragma unroll
    for (int mi = 0; mi < 4; ++mi) {
      const int m = m0 + wm * 64 + mi * 16 + kg * 4;
#pragma unroll
      for (int r = 0; r < 4; ++r) {
        out[(size_t)(m + r) * 768 + n] = acc[mi][ni][r] + bias;
      }
    }
  }
}

// ---------------- 2. forward row rFFT via MFMA (round-16 structure) --------
__global__ __launch_bounds__(256) void rfft_row_mfma_kernel(
    const float* __restrict__ x, unsigned short* __restrict__ xbf,
    unsigned short* __restrict__ XFr, unsigned short* __restrict__ XFi) {
  __shared__ alignas(16) unsigned short Cs[48 * 80];   //  0.125*cos [kh][w]
  __shared__ alignas(16) unsigned short Ss[48 * 80];   // -0.125*sin
  __shared__ alignas(16) unsigned short xs[64 * 66];   // [w][c] stride 66
  const int t = threadIdx.x;
  for (int e = t; e < 48 * 64; e += 256) {
    const int kh = e >> 6;
    const int w = e & 63;
    const float ang = (float)(2.0 * M_PI / 64.0) * (float)((kh * w) & 63);
    float s_, c_;
    __sincosf(ang, &s_, &c_);
    Cs[kh * 80 + w] = f2bf(0.125f * c_);
    Ss[kh * 80 + w] = f2bf(-0.125f * s_);
  }

  const int lane = t & 63;
  const int wv = t >> 6;       // wave id
  const int cl = lane & 15;
  const int kg = lane >> 4;    // 0..3
  const int bh = blockIdx.x;   // b*64 + h
  const int b = bh >> 6;
  const int h = bh & 63;
  const int c0 = blockIdx.y * 64;

  // ---- stage: wave wv covers w = wv*16..+15; lane -> (w parity, 2 chans) --
  {
    const float* xrow = x + (size_t)bh * (64 * 768) + c0;
    unsigned short* xbrow = xbf + (size_t)bh * (64 * 768) + c0;
    const int wofs = lane >> 5;        // 0..1
    const int c2 = (lane & 31) * 2;    // even channel
#pragma unroll
    for (int it = 0; it < 8; ++it) {
      const int w = wv * 16 + it * 2 + wofs;
      const float2 v = *reinterpret_cast<const float2*>(xrow + (size_t)w * 768 + c2);
      ushort2 bv;
      bv.x = f2bf(v.x);
      bv.y = f2bf(v.y);
      *reinterpret_cast<ushort2*>(xbrow + (size_t)w * 768 + c2) = bv;
      *reinterpret_cast<ushort2*>(xs + w * 66 + c2) = bv;
    }
  }
  __syncthreads();

  // A fragments: lane holds x[w = kf*32+kg*8+j][c = c0 + wv*16 + cl]
  const int cA = wv * 16 + cl;
  short8 ax[2];
#pragma unroll
  for (int kf = 0; kf < 2; ++kf) {
#pragma unroll
    for (int j = 0; j < 8; ++j)
      ax[kf][j] = (short)xs[(kf * 32 + kg * 8 + j) * 66 + cA];
  }

  f32x4 aR[3], aI[3];
#pragma unroll
  for (int nt = 0; nt < 3; ++nt) {
    aR[nt] = (f32x4){0.f, 0.f, 0.f, 0.f};
    aI[nt] = (f32x4){0.f, 0.f, 0.f, 0.f};
  }

#pragma unroll
  for (int nt = 0; nt < 3; ++nt) {
#pragma unroll
    for (int kf = 0; kf < 2; ++kf) {
      const int row = nt * 16 + cl;       // kh
      const int w0 = kf * 32 + kg * 8;
      const bf16x8 bc = *reinterpret_cast<const bf16x8*>(Cs + row * 80 + w0);
      const bf16x8 bs = *reinterpret_cast<const bf16x8*>(Ss + row * 80 + w0);
      aR[nt] = __builtin_amdgcn_mfma_f32_16x16x32_bf16(s2b(ax[kf]), bc, aR[nt], 0, 0, 0);
      aI[nt] = __builtin_amdgcn_mfma_f32_16x16x32_bf16(s2b(ax[kf]), bs, aI[nt], 0, 0, 0);
    }
  }

  // store: lane holds kh = nt*16+cl, c = c0 + wv*16 + kg*4 + (0..3)
  const int cD = c0 + wv * 16 + kg * 4;
#pragma unroll
  for (int nt = 0; nt < 3; ++nt) {
    const int kh = nt * 16 + cl;
    if (kh <= 32) {
      const size_t off = (((size_t)b * kNKW + kh) * 64 + h) * 768 + cD;
      ushort4 vr, vi;
      vr.x = f2bf(aR[nt][0]); vr.y = f2bf(aR[nt][1]);
      vr.z = f2bf(aR[nt][2]); vr.w = f2bf(aR[nt][3]);
      vi.x = f2bf(aI[nt][0]); vi.y = f2bf(aI[nt][1]);
      vi.z = f2bf(aI[nt][2]); vi.w = f2bf(aI[nt][3]);
      *reinterpret_cast<ushort4*>(XFr + off) = vr;
      *reinterpret_cast<ushort4*>(XFi + off) = vi;
    }
  }
}

// ---------------- 3+4+5 fused: col FFT -> MLP -> col iFFT (r16 ping-pong) --
__global__ __launch_bounds__(256) void spectral_mid_kernel(
    unsigned short* __restrict__ Xr, unsigned short* __restrict__ Xi,
    const float* __restrict__ b1, const float* __restrict__ b2) {
  __shared__ alignas(16) unsigned short sXr[64 * 104];
  __shared__ alignas(16) unsigned short sXi[64 * 104];
  __shared__ alignas(16) unsigned short sYr[64 * 104];
  __shared__ alignas(16) unsigned short sYi[64 * 104];
  const int t = threadIdx.x;
  const int lane = t & 63;
  const int wid = t >> 6;   // 0..3
  const int wm = wid >> 1;  // 0..1
  const int wn = wid & 1;   // 0..1
  const int cl = lane & 15;
  const int kg = lane >> 4;
  const int nb = blockIdx.y;
  const size_t gbase = (size_t)blockIdx.x * (64 * 768) + nb * 96;

  // ---- prefetch twiddle fragments (shared by steps A and D) ----
  short8 pcs[2][2], pss[2][2];  // [mt][kf]
#pragma unroll
  for (int mt = 0; mt < 2; ++mt) {
#pragma unroll
    for (int kf = 0; kf < 2; ++kf) {
      const int row = wm * 32 + mt * 16 + cl;
      const int k0 = kf * 32 + kg * 8;
      pcs[mt][kf] = *reinterpret_cast<const short8*>(g_twC + row * 64 + k0);
      pss[mt][kf] = *reinterpret_cast<const short8*>(g_twS + row * 64 + k0);
    }
  }

  // ---- load tile [row=h][col=c] ----
  {
    const int row = t >> 2;
    const int q = t & 3;  // 24-elem chunk
    const size_t gof = gbase + (size_t)row * 768 + q * 24;
    unsigned short* lr = sXr + row * 104 + q * 24;
    unsigned short* li = sXi + row * 104 + q * 24;
#pragma unroll
    for (int v = 0; v < 3; ++v) {
      *reinterpret_cast<short8*>(lr + v * 8) =
          *reinterpret_cast<const short8*>(Xr + gof + v * 8);
      *reinterpret_cast<short8*>(li + v * 8) =
          *reinterpret_cast<const short8*>(Xi + gof + v * 8);
    }
  }
  __syncthreads();

  f32x4 accR[2][3], accI[2][3];

  // ================= step A: forward FFT along h =================
#pragma unroll
  for (int mt = 0; mt < 2; ++mt)
#pragma unroll
    for (int nt = 0; nt < 3; ++nt) {
      accR[mt][nt] = (f32x4){0.f, 0.f, 0.f, 0.f};
      accI[mt][nt] = (f32x4){0.f, 0.f, 0.f, 0.f};
    }
#pragma unroll
  for (int kf = 0; kf < 2; ++kf) {
    const int k0 = kf * 32 + kg * 8;
    short8 bR[3], bI[3];
#pragma unroll
    for (int nt = 0; nt < 3; ++nt) {
      const int col = wn * 48 + nt * 16 + cl;
#pragma unroll
      for (int j = 0; j < 8; ++j) {
        bR[nt][j] = (short)sXr[(k0 + j) * 104 + col];
        bI[nt][j] = (short)sXi[(k0 + j) * 104 + col];
      }
    }
#pragma unroll
    for (int mt = 0; mt < 2; ++mt) {
      const short8 cs = pcs[mt][kf];
      const short8 ss = pss[mt][kf];
#pragma unroll
      for (int nt = 0; nt < 3; ++nt) {
        accR[mt][nt] = __builtin_amdgcn_mfma_f32_16x16x32_bf16(s2b(cs), s2b(bR[nt]), accR[mt][nt], 0, 0, 0);
        accR[mt][nt] = __builtin_amdgcn_mfma_f32_16x16x32_bf16(s2b(ss), s2b(bI[nt]), accR[mt][nt], 0, 0, 0);
        accI[mt][nt] = __builtin_amdgcn_mfma_f32_16x16x32_bf16(s2b(cs), s2b(bI[nt]), accI[mt][nt], 0, 0, 0);
        accI[mt][nt] = __builtin_amdgcn_mfma_f32_16x16x32_bf16(negb(ss), s2b(bR[nt]), accI[mt][nt], 0, 0, 0);
      }
    }
  }
  // write to sY [kh][c]
#pragma unroll
  for (int mt = 0; mt < 2; ++mt) {
#pragma unroll
    for (int nt = 0; nt < 3; ++nt) {
      const int col = wn * 48 + nt * 16 + cl;
      const int row0 = wm * 32 + mt * 16 + kg * 4;
#pragma unroll
      for (int r = 0; r < 4; ++r) {
        sYr[(row0 + r) * 104 + col] = f2bf(accR[mt][nt][r]);
        sYi[(row0 + r) * 104 + col] = f2bf(accI[mt][nt][r]);
      }
    }
  }
  __syncthreads();

  const unsigned short* wt1r = g_wT + (size_t)(0 * 8 + nb) * 9216;
  const unsigned short* wt1i = g_wT + (size_t)(1 * 8 + nb) * 9216;
  const unsigned short* wt2r = g_wT + (size_t)(2 * 8 + nb) * 9216;
  const unsigned short* wt2i = g_wT + (size_t)(3 * 8 + nb) * 9216;

  // ================= step B: MLP layer 1 (read sY, write sX) =========
#pragma unroll
  for (int mt = 0; mt < 2; ++mt)
#pragma unroll
    for (int nt = 0; nt < 3; ++nt) {
      accR[mt][nt] = (f32x4){0.f, 0.f, 0.f, 0.f};
      accI[mt][nt] = (f32x4){0.f, 0.f, 0.f, 0.f};
    }
#pragma unroll
  for (int kk = 0; kk < 3; ++kk) {
    const int ko = kk * 32 + kg * 8;
    short8 axr[2], axi[2];
#pragma unroll
    for (int mt = 0; mt < 2; ++mt) {
      const int row = wm * 32 + mt * 16 + cl;
      axr[mt] = *reinterpret_cast<const short8*>(sYr + row * 104 + ko);
      axi[mt] = *reinterpret_cast<const short8*>(sYi + row * 104 + ko);
    }
    short8 wr_[3], wi_[3];
#pragma unroll
    for (int nt = 0; nt < 3; ++nt) {
      const int rw = wn * 48 + nt * 16 + cl;
      wr_[nt] = *reinterpret_cast<const short8*>(wt1r + rw * 96 + ko);
      wi_[nt] = *reinterpret_cast<const short8*>(wt1i + rw * 96 + ko);
    }
#pragma unroll
    for (int mt = 0; mt < 2; ++mt) {
      const bf16x8 ar = s2b(axr[mt]);
      const bf16x8 ai = s2b(axi[mt]);
      const bf16x8 ain = negb(axi[mt]);
#pragma unroll
      for (int nt = 0; nt < 3; ++nt) {
        accR[mt][nt] = __builtin_amdgcn_mfma_f32_16x16x32_bf16(ar, s2b(wr_[nt]), accR[mt][nt], 0, 0, 0);
        accR[mt][nt] = __builtin_amdgcn_mfma_f32_16x16x32_bf16(ain, s2b(wi_[nt]), accR[mt][nt], 0, 0, 0);
        accI[mt][nt] = __builtin_amdgcn_mfma_f32_16x16x32_bf16(ar, s2b(wi_[nt]), accI[mt][nt], 0, 0, 0);
        accI[mt][nt] = __builtin_amdgcn_mfma_f32_16x16x32_bf16(ai, s2b(wr_[nt]), accI[mt][nt], 0, 0, 0);
      }
    }
  }
  // bias + relu -> sX
#pragma unroll
  for (int nt = 0; nt < 3; ++nt) {
    const int col = wn * 48 + nt * 16 + cl;
    const float br = b1[nb * 96 + col];
    const float bi = b1[768 + nb * 96 + col];
#pragma unroll
    for (int mt = 0; mt < 2; ++mt) {
      const int row0 = wm * 32 + mt * 16 + kg * 4;
#pragma unroll
      for (int r = 0; r < 4; ++r) {
        sXr[(row0 + r) * 104 + col] = f2bf(fmaxf(accR[mt][nt][r] + br, 0.f));
        sXi[(row0 + r) * 104 + col] = f2bf(fmaxf(accI[mt][nt][r] + bi, 0.f));
      }
    }
  }
  __syncthreads();

  // ================= step C: MLP layer 2 (read sX, write sY) =========
#pragma unroll
  for (int mt = 0; mt < 2; ++mt)
#pragma unroll
    for (int nt = 0; nt < 3; ++nt) {
      accR[mt][nt] = (f32x4){0.f, 0.f, 0.f, 0.f};
      accI[mt][nt] = (f32x4){0.f, 0.f, 0.f, 0.f};
    }
#pragma unroll
  for (int kk = 0; kk < 3; ++kk) {
    const int ko = kk * 32 + kg * 8;
    short8 axr[2], axi[2];
#pragma unroll
    for (int mt = 0; mt < 2; ++mt) {
      const int row = wm * 32 + mt * 16 + cl;
      axr[mt] = *reinterpret_cast<const short8*>(sXr + row * 104 + ko);
      axi[mt] = *reinterpret_cast<const short8*>(sXi + row * 104 + ko);
    }
    short8 wr_[3], wi_[3];
#pragma unroll
    for (int nt = 0; nt < 3; ++nt) {
      const int rw = wn * 48 + nt * 16 + cl;
      wr_[nt] = *reinterpret_cast<const short8*>(wt2r + rw * 96 + ko);
      wi_[nt] = *reinterpret_cast<const short8*>(wt2i + rw * 96 + ko);
    }
#pragma unroll
    for (int mt = 0; mt < 2; ++mt) {
      const bf16x8 ar = s2b(axr[mt]);
      const bf16x8 ai = s2b(axi[mt]);
      const bf16x8 ain = negb(axi[mt]);
#pragma unroll
      for (int nt = 0; nt < 3; ++nt) {
        accR[mt][nt] = __builtin_amdgcn_mfma_f32_16x16x32_bf16(ar, s2b(wr_[nt]), accR[mt][nt], 0, 0, 0);
        accR[mt][nt] = __builtin_amdgcn_mfma_f32_16x16x32_bf16(ain, s2b(wi_[nt]), accR[mt][nt], 0, 0, 0);
        accI[mt][nt] = __builtin_amdgcn_mfma_f32_16x16x32_bf16(ar, s2b(wi_[nt]), accI[mt][nt], 0, 0, 0);
        accI[mt][nt] = __builtin_amdgcn_mfma_f32_16x16x32_bf16(ai, s2b(wr_[nt]), accI[mt][nt], 0, 0, 0);
      }
    }
  }
  // bias + softshrink -> sY
#pragma unroll
  for (int nt = 0; nt < 3; ++nt) {
    const int col = wn * 48 + nt * 16 + cl;
    const float br = b2[nb * 96 + col];
    const float bi = b2[768 + nb * 96 + col];
#pragma unroll
    for (int mt = 0; mt < 2; ++mt) {
      const int row0 = wm * 32 + mt * 16 + kg * 4;
#pragma unroll
      for (int r = 0; r < 4; ++r) {
        float vr = accR[mt][nt][r] + br;
        float vi = accI[mt][nt][r] + bi;
        vr = (vr > kLambd) ? (vr - kLambd) : ((vr < -kLambd) ? (vr + kLambd) : 0.f);
        vi = (vi > kLambd) ? (vi - kLambd) : ((vi < -kLambd) ? (vi + kLambd) : 0.f);
        sYr[(row0 + r) * 104 + col] = f2bf(vr);
        sYi[(row0 + r) * 104 + col] = f2bf(vi);
      }
    }
  }
  __syncthreads();

  // ================= step D: inverse FFT along kh, write global ======
#pragma unroll
  for (int mt = 0; mt < 2; ++mt)
#pragma unroll
    for (int nt = 0; nt < 3; ++nt) {
      accR[mt][nt] = (f32x4){0.f, 0.f, 0.f, 0.f};
      accI[mt][nt] = (f32x4){0.f, 0.f, 0.f, 0.f};
    }
#pragma unroll
  for (int kf = 0; kf < 2; ++kf) {
    const int k0 = kf * 32 + kg * 8;
    short8 bR[3], bI[3];
#pragma unroll
    for (int nt = 0; nt < 3; ++nt) {
      const int col = wn * 48 + nt * 16 + cl;
#pragma unroll
      for (int j = 0; j < 8; ++j) {
        bR[nt][j] = (short)sYr[(k0 + j) * 104 + col];
        bI[nt][j] = (short)sYi[(k0 + j) * 104 + col];
      }
    }
#pragma unroll
    for (int mt = 0; mt < 2; ++mt) {
      const short8 cs = pcs[mt][kf];
      const short8 ss = pss[mt][kf];
#pragma unroll
      for (int nt = 0; nt < 3; ++nt) {
        accR[mt][nt] = __builtin_amdgcn_mfma_f32_16x16x32_bf16(s2b(cs), s2b(bR[nt]), accR[mt][nt], 0, 0, 0);
        accR[mt][nt] = __builtin_amdgcn_mfma_f32_16x16x32_bf16(negb(ss), s2b(bI[nt]), accR[mt][nt], 0, 0, 0);
        accI[mt][nt] = __builtin_amdgcn_mfma_f32_16x16x32_bf16(s2b(cs), s2b(bI[nt]), accI[mt][nt], 0, 0, 0);
        accI[mt][nt] = __builtin_amdgcn_mfma_f32_16x16x32_bf16(s2b(ss), s2b(bR[nt]), accI[mt][nt], 0, 0, 0);
      }
    }
  }
  // write final tile back to global (in place)
#pragma unroll
  for (int mt = 0; mt < 2; ++mt) {
#pragma unroll
    for (int nt = 0; nt < 3; ++nt) {
      const int col = wn * 48 + nt * 16 + cl;
      const int row0 = wm * 32 + mt * 16 + kg * 4;
#pragma unroll
      for (int r = 0; r < 4; ++r) {
        const size_t off = gbase + (size_t)(row0 + r) * 768 + col;
        Xr[off] = f2bf(accR[mt][nt][r]);
        Xi[off] = f2bf(accI[mt][nt][r]);
      }
    }
  }
}

// ---------------- 6. inverse row rDFT + accumulate via MFMA (swapped) ------
__global__ __launch_bounds__(256) void irfft_row_add_mfma_kernel(
    const unsigned short* __restrict__ Zr, const unsigned short* __restrict__ Zi,
    float* __restrict__ out) {
  const int t = threadIdx.x;
  const int lane = t & 63;
  const int wv = t >> 6;
  const int cl = lane & 15;
  const int kg = lane >> 4;
  const int bh = blockIdx.x;  // b*64 + h
  const int b = bh >> 6;
  const int h = bh & 63;
  const int cb = blockIdx.y * 64 + wv * 16;  // wave's 16-channel strip

  // ---- prefetch irfft table fragments ----
  short8 pbc[4][2], pbs[4][2];  // [nt][kf]
#pragma unroll
  for (int nt = 0; nt < 4; ++nt) {
#pragma unroll
    for (int kf = 0; kf < 2; ++kf) {
      const int row = nt * 16 + cl;
      const int kw0 = kf * 32 + kg * 8;
      pbc[nt][kf] = *reinterpret_cast<const short8*>(g_iwC + row * 64 + kw0);
      pbs[nt][kf] = *reinterpret_cast<const short8*>(g_iwS + row * 64 + kw0);
    }
  }

  // A fragments: lane holds Z[c = cb + cl][kw = kf*32+kg*8+j]
  const int cA = cb + cl;
  short8 azr[2], azi[2];
#pragma unroll
  for (int kf = 0; kf < 2; ++kf) {
#pragma unroll
    for (int j = 0; j < 8; ++j) {
      const int kw = kf * 32 + kg * 8 + j;
      short zr = 0, zi = 0;
      if (kw < 33) {
        const size_t off = (((size_t)b * kNKW + kw) * 64 + h) * 768 + cA;
        zr = (short)Zr[off];
        zi = (short)Zi[off];
      }
      azr[kf][j] = zr;
      azi[kf][j] = zi;
    }
  }

  // preload accumulator with bias-path out values (float4 per lane)
  const int cD = cb + kg * 4;
  float* obase = out + ((size_t)bh * 64) * 768;
  f32x4 aO[4];
#pragma unroll
  for (int nt = 0; nt < 4; ++nt) {
    const int w = nt * 16 + cl;
    aO[nt] = *reinterpret_cast<const f32x4*>(obase + (size_t)w * 768 + cD);
  }

#pragma unroll
  for (int nt = 0; nt < 4; ++nt) {
#pragma unroll
    for (int kf = 0; kf < 2; ++kf) {
      aO[nt] = __builtin_amdgcn_mfma_f32_16x16x32_bf16(s2b(azr[kf]), s2b(pbc[nt][kf]), aO[nt], 0, 0, 0);
      aO[nt] = __builtin_amdgcn_mfma_f32_16x16x32_bf16(s2b(azi[kf]), s2b(pbs[nt][kf]), aO[nt], 0, 0, 0);
    }
  }

#pragma unroll
  for (int nt = 0; nt < 4; ++nt) {
    const int w = nt * 16 + cl;
    *reinterpret_cast<f32x4*>(obase + (size_t)w * 768 + cD) = aO[nt];
  }
}

}  // namespace

extern "C" void kernel_launch(void* const* d_in, const int* in_sizes, int n_in,
                              void* d_out, int out_size, void* d_ws,
                              size_t ws_size, hipStream_t stream) {
  (void)in_sizes; (void)n_in; (void)out_size;
  const float* x  = (const float*)d_in[0];
  const float* w1 = (const float*)d_in[1];
  const float* b1 = (const float*)d_in[2];
  const float* w2 = (const float*)d_in[3];
  const float* b2 = (const float*)d_in[4];
  const float* Wb = (const float*)d_in[5];
  const float* bb = (const float*)d_in[6];
  float* out = (float*)d_out;

  // ws layout (all bf16): xbf 48MB | wbf 1.2MB | XFr 26MB | XFi 26MB = 103.4MB
  if (ws_size < 2 * kXFElems * sizeof(float)) return;
  unsigned short* xbf = (unsigned short*)d_ws;      // 32768*768
  unsigned short* wbf = xbf + (size_t)32768 * 768;  // 768*768
  unsigned short* XFr = wbf + (size_t)768 * 768;    // kXFElems
  unsigned short* XFi = XFr + kXFElems;             // kXFElems

  // 0. one-shot conversions and tables
  init_tables_kernel<<<dim3(16), 256, 0, stream>>>();
  cvt_f32_bf16_kernel<<<dim3((768 * 768 / 4 + 255) / 256), 256, 0, stream>>>(
      Wb, wbf, 768 * 768 / 4);
  cvt_w_kernel<<<dim3(4 * 8 * 96 * 96 / 256), 256, 0, stream>>>(w1, w2);
  // 2. forward row rFFT on matrix cores (bf16 out) + fused x->bf16 for GEMM
  rfft_row_mfma_kernel<<<dim3(512, 12), 256, 0, stream>>>(x, xbf, XFr, XFi);
  // 1. bias path GEMM on matrix cores (writes d_out fully)
  mfma_gemm_kernel<<<dim3(1536), 256, 0, stream>>>(xbf, wbf, bb, out);
  // 3-5. fused: column FFT -> block-diag MLP -> column iFFT (in place)
  spectral_mid_kernel<<<dim3(264, 8), 256, 0, stream>>>(XFr, XFi, b1, b2);
  // 6. inverse row rDFT + add bias path on matrix cores
  irfft_row_add_mfma_kernel<<<dim3(512, 12), 256, 0, stream>>>(XFr, XFi, out);
}